// Round 9
// baseline (685.972 us; speedup 1.0000x reference)
//
#include <hip/hip_runtime.h>
#include <hip/hip_bf16.h>

typedef unsigned int uint;
typedef unsigned short ushort;
typedef float f32x4 __attribute__((ext_vector_type(4)));
typedef short s16x8 __attribute__((ext_vector_type(8)));
typedef int i32x4 __attribute__((ext_vector_type(4)));
typedef uint u32x2 __attribute__((ext_vector_type(2)));

#define C_DIM 8192
#define B_DIM 1024
#define P_DIM 3
#define E_DIM 64
#define M_DIM 128

// workspace layout (bytes)
#define PCA_OFF   0ull                    // path_card hi/lo tile images: 3*256*20480 = 15728640
#define PART_OFF  15728640ull             // K2 partials fp32: 4*3*128*8192*4 = 50331648
#define PCMH_OFF  66060288ull             // pcm hi bf16: 6291456
#define PCML_OFF  72351744ull             // pcm lo bf16: 6291456
#define XPART_OFF PART_OFF                // x partials alias K2 partials (dead by then)
#define NPOOL_OFF 78643200ull             // 1024*64*2
#define NCARD_OFF 78774272ull             // 8192*64*2

__device__ __forceinline__ uint bf16_rne(float f) {
  uint u = __builtin_bit_cast(uint, f);
  return (u + 0x7fffu + ((u >> 16) & 1u)) >> 16;
}
__device__ __forceinline__ float bf16_to_f32(uint b) {
  return __builtin_bit_cast(float, b << 16);
}
// pack 2 f32 -> 2 bf16 (RNE) in one word: low16=a, high16=b
__device__ __forceinline__ uint pk2(float a, float b) {
  float2 t; t.x = a; t.y = b;
  __hip_bfloat162 h2 = __float22bfloat162_rn(t);
  uint r;
  __builtin_memcpy(&r, &h2, 4);
  return r;
}

// ---------------- K1: path_card = silu(ce @ ker + bias), split hi/lo bf16,
// stored as fragment-layout tile images [p][kt=c/32][m*80 + kl*2] (+10240 for lo)
__global__ __launch_bounds__(256) void k1_pathcard(
    const float* __restrict__ cardemb, const float* __restrict__ mpk,
    const float* __restrict__ mpbias, ushort* __restrict__ pcA) {
  __shared__ float ce_l[64 * 68];
  const int tid = threadIdx.x;
  const int cb = blockIdx.x;  // 0..127 (64 c's each)
  const int p  = blockIdx.y;  // 0..2
  for (int r = 0; r < 16; ++r) {
    int i = r * 256 + tid;
    int row = i >> 6, col = i & 63;
    ce_l[row * 68 + col] = cardemb[(size_t)(cb * 64 + row) * 64 + col];
  }
  __syncthreads();
  const int m = tid & 127;
  const int chalf = tid >> 7;
  float kr[64];
#pragma unroll
  for (int e = 0; e < 64; ++e) kr[e] = mpk[(size_t)p * E_DIM * M_DIM + e * M_DIM + m];
  const float bias = mpbias[p * M_DIM + m];
  for (int cl0 = 0; cl0 < 32; ++cl0) {
    int cl = chalf * 32 + cl0;
    float acc = bias;
#pragma unroll
    for (int e = 0; e < 64; ++e) acc += ce_l[cl * 68 + e] * kr[e];
    float s = acc / (1.0f + expf(-acc));  // silu
    uint hb = bf16_rne(s);
    uint lb = bf16_rne(s - bf16_to_f32(hb));
    int c = cb * 64 + cl;
    int kt = c >> 5, kl = c & 31;
    size_t off = ((size_t)(p * 256 + kt) * 20480 + (size_t)m * 80 + (size_t)kl * 2) >> 1;
    pcA[off] = (ushort)hb;
    pcA[off + 5120] = (ushort)lb;  // +10240 bytes
  }
}

// ---------------- K2: partial[q][p] = pcA(128 x 2048) @ metapaths[p](2048 x 8192)
// 3-term bf16 split MFMA. A fragments straight from global (L2-resident pcA).
// B: 3-register-buffer pipeline (loads issued 3 steps ahead -> 2 tiles = 32 KB
// per block ALWAYS in flight across barriers; vmcnt never drained) feeding an
// LDS double buffer (XOR-swizzled). One raw s_barrier per step. 32 KB LDS ->
// 3 blocks/CU.
__global__ __launch_bounds__(256, 3) void k2_big(
    const float* __restrict__ mp, const ushort* __restrict__ pcA,
    float* __restrict__ partial) {
  __shared__ char smem[32768];  // B0[0,16384) B1[16384,32768); each: hi 8K + lo 8K
  const int tid = threadIdx.x;
  int lin = blockIdx.x + 64 * (blockIdx.y + 4 * blockIdx.z);   // 0..767
  int swz = (lin & 7) * 96 + (lin >> 3);                        // XCD-chunked
  const int dt = swz & 63, q = (swz >> 6) & 3, p = swz >> 8;
  const int lane = tid & 63, wid = tid >> 6;
  const int wr = wid >> 1, wc = wid & 1;
  const int r16 = lane & 15, g4 = lane >> 4;
  const float* mpb = mp + (size_t)p * C_DIM * C_DIM + (size_t)dt * 128;
  const char* pcb = (const char*)pcA + (size_t)(p * 256 + q * 64) * 20480;
  const int sd = tid & 127, skh = tid >> 7;
  const int fc = ((sd ^ (sd >> 2)) & 3) << 4;    // write-side XOR swizzle
  const int fr = ((r16 ^ (r16 >> 2)) & 3) << 4;  // read-side XOR swizzle

  f32x4 acc[4][4];
#pragma unroll
  for (int i = 0; i < 4; ++i)
#pragma unroll
    for (int j = 0; j < 4; ++j) acc[i][j] = (f32x4){0.f, 0.f, 0.f, 0.f};

  auto loadB = [&](int t, float* br) {
    int c0 = q * 2048 + t * 32;
#pragma unroll
    for (int ii = 0; ii < 2; ++ii) {
      const float* rp = mpb + (size_t)(c0 + ii * 16 + skh * 8) * C_DIM + sd;
#pragma unroll
      for (int j = 0; j < 8; ++j) br[ii * 8 + j] = rp[(size_t)j * C_DIM];
    }
  };
  auto writeB = [&](const float* br, int buf) {
    char* bb = smem + buf * 16384;
#pragma unroll
    for (int ii = 0; ii < 2; ++ii) {
      uint hw[4], lw[4];
#pragma unroll
      for (int k2 = 0; k2 < 4; ++k2) {
        float v0 = br[ii * 8 + k2 * 2], v1 = br[ii * 8 + k2 * 2 + 1];
        uint h = pk2(v0, v1);
        float h0 = __builtin_bit_cast(float, h << 16);
        float h1 = __builtin_bit_cast(float, h & 0xffff0000u);
        hw[k2] = h;
        lw[k2] = pk2(v0 - h0, v1 - h1);
      }
      int off = sd * 64 + ((((ii * 2 + skh) << 4)) ^ fc);
      *(i32x4*)(bb + off) = (i32x4){(int)hw[0], (int)hw[1], (int)hw[2], (int)hw[3]};
      *(i32x4*)(bb + 8192 + off) = (i32x4){(int)lw[0], (int)lw[1], (int)lw[2], (int)lw[3]};
    }
  };
  auto compute = [&](int t, int buf) {
    const char* At = pcb + (size_t)t * 20480;
    const char* Bb = smem + buf * 16384;
    s16x8 ah[4], al[4], bh[4], bl[4];
#pragma unroll
    for (int i = 0; i < 4; ++i) {
      int off = (wr * 64 + i * 16 + r16) * 80 + g4 * 16;
      ah[i] = *(const s16x8*)(At + off);          // global, L2-hit
      al[i] = *(const s16x8*)(At + 10240 + off);
    }
#pragma unroll
    for (int j = 0; j < 4; ++j) {
      int off = (wc * 64 + j * 16 + r16) * 64 + ((g4 << 4) ^ fr);
      bh[j] = *(const s16x8*)(Bb + off);
      bl[j] = *(const s16x8*)(Bb + 8192 + off);
    }
#pragma unroll
    for (int i = 0; i < 4; ++i)
#pragma unroll
      for (int j = 0; j < 4; ++j) {
        acc[i][j] = __builtin_amdgcn_mfma_f32_16x16x32_bf16(ah[i], bh[j], acc[i][j], 0, 0, 0);
        acc[i][j] = __builtin_amdgcn_mfma_f32_16x16x32_bf16(ah[i], bl[j], acc[i][j], 0, 0, 0);
        acc[i][j] = __builtin_amdgcn_mfma_f32_16x16x32_bf16(al[i], bh[j], acc[i][j], 0, 0, 0);
      }
  };

  float br0[16], br1[16], br2[16];
  // prologue: issue B(0),B(1),B(2); write B(0) -> LDS buf0 (waits only br0's
  // loads; B(1)/B(2) stay in flight across the barrier).
  loadB(0, br0);
  loadB(1, br1);
  loadB(2, br2);
  writeB(br0, 0);
  asm volatile("s_waitcnt lgkmcnt(0)" ::: "memory");
  __builtin_amdgcn_s_barrier();
  __builtin_amdgcn_sched_barrier(0);

  // step T: issue loadB(T+3) into the buffer freed by last step's write;
  // compute(T) from LDS buf[T&1]; convert+write B(T+1) -> buf[(T+1)&1];
  // lgkmcnt(0) only (vmcnt NEVER drained); one raw barrier.
#define K2S(T, BRL, BRW)                                                      \
  {                                                                           \
    if ((T) + 3 < 64) loadB((T) + 3, BRL);                                    \
    compute((T), (T) & 1);                                                    \
    if ((T) < 63) {                                                           \
      writeB(BRW, ((T) + 1) & 1);                                             \
      asm volatile("s_waitcnt lgkmcnt(0)" ::: "memory");                      \
      __builtin_amdgcn_s_barrier();                                           \
      __builtin_amdgcn_sched_barrier(0);                                      \
    }                                                                         \
  }

  // 6-step period: B-buffer rotation (3) x LDS parity (2). 64 = 6*10 + 4.
  for (int i6 = 0; i6 < 10; ++i6) {
    int t = 6 * i6;
    K2S(t + 0, br0, br1);
    K2S(t + 1, br1, br2);
    K2S(t + 2, br2, br0);
    K2S(t + 3, br0, br1);
    K2S(t + 4, br1, br2);
    K2S(t + 5, br2, br0);
  }
  K2S(60, br0, br1);
  K2S(61, br1, br2);
  K2S(62, br2, br0);
  K2S(63, br0, br1);
#undef K2S

  float* part = partial + (size_t)(q * 3 + p) * M_DIM * C_DIM + (size_t)dt * 128;
#pragma unroll
  for (int i = 0; i < 4; ++i)
#pragma unroll
    for (int j = 0; j < 4; ++j)
#pragma unroll
      for (int r = 0; r < 4; ++r)
        part[(size_t)(wr * 64 + i * 16 + g4 * 4 + r) * C_DIM + (wc * 64 + j * 16 + r16)] =
            acc[i][j][r];
}

// ---------------- K2b: pcm = sum of 4 q-partials, split to hi/lo bf16 [p][m][d]
__global__ __launch_bounds__(256) void k2b_reduce(const float* __restrict__ p0,
                                                  ushort* __restrict__ oh,
                                                  ushort* __restrict__ ol) {
  size_t i = (size_t)blockIdx.x * 256 + threadIdx.x;  // 786432 threads, 4 elems each
  f32x4 a = *(const f32x4*)(p0 + i * 4);
  f32x4 b = *(const f32x4*)(p0 + 3145728ull + i * 4);
  f32x4 c = *(const f32x4*)(p0 + 6291456ull + i * 4);
  f32x4 d = *(const f32x4*)(p0 + 9437184ull + i * 4);
  f32x4 s = (a + b) + (c + d);
  uint h[2], l[2];
#pragma unroll
  for (int k = 0; k < 2; ++k) {
    float v0 = s[k * 2], v1 = s[k * 2 + 1];
    uint hh = pk2(v0, v1);
    float h0 = __builtin_bit_cast(float, hh << 16);
    float h1 = __builtin_bit_cast(float, hh & 0xffff0000u);
    h[k] = hh;
    l[k] = pk2(v0 - h0, v1 - h1);
  }
  *(u32x2*)(oh + i * 4) = (u32x2){h[0], h[1]};
  *(u32x2*)(ol + i * 4) = (u32x2){l[0], l[1]};
}

// ---------------- K3: x = pools @ pcm^T, 3-term split, pure-register MFMA.
// Grid 32 bt x 16 ks = 512 blocks (2/CU, 2 waves/SIMD). Block = 32 rows x 384
// cols; each wave owns 96 cols (spanning p). One-step A (pools) prefetch.
__global__ __launch_bounds__(256, 2) void k3_x(const float* __restrict__ pools,
                                               const ushort* __restrict__ pcmh,
                                               const ushort* __restrict__ pcml,
                                               float* __restrict__ xpart) {
  const int tid = threadIdx.x;
  const int bt = blockIdx.x, ks = blockIdx.y;
  const int lane = tid & 63, w = tid >> 6;
  const int r16 = lane & 15, g4 = lane >> 4;
  const int rowbase = bt * 32;
  f32x4 acc[2][6];
#pragma unroll
  for (int i = 0; i < 2; ++i)
#pragma unroll
    for (int j = 0; j < 6; ++j) acc[i][j] = (f32x4){0.f, 0.f, 0.f, 0.f};

  f32x4 pv0[2], pv1[2];
#pragma unroll
  for (int i = 0; i < 2; ++i) {
    const float* ap = pools + (size_t)(rowbase + i * 16 + r16) * C_DIM + ks * 512 + g4 * 8;
    pv0[i] = *(const f32x4*)ap;
    pv1[i] = *(const f32x4*)(ap + 4);
  }

  for (int t = 0; t < 16; ++t) {
    int d0 = ks * 512 + t * 32 + g4 * 8;
    // convert current A vecs
    s16x8 ah[2], al[2];
#pragma unroll
    for (int i = 0; i < 2; ++i) {
      i32x4 hw, lw;
#pragma unroll
      for (int k2 = 0; k2 < 4; ++k2) {
        float x0 = (k2 < 2) ? pv0[i][k2 * 2] : pv1[i][(k2 - 2) * 2];
        float x1 = (k2 < 2) ? pv0[i][k2 * 2 + 1] : pv1[i][(k2 - 2) * 2 + 1];
        uint h = pk2(x0, x1);
        float h0 = __builtin_bit_cast(float, h << 16);
        float h1 = __builtin_bit_cast(float, h & 0xffff0000u);
        hw[k2] = (int)h;
        lw[k2] = (int)pk2(x0 - h0, x1 - h1);
      }
      ah[i] = __builtin_bit_cast(s16x8, hw);
      al[i] = __builtin_bit_cast(s16x8, lw);
    }
    // prefetch next-t A vecs (independent of this t's MFMA)
    if (t < 15) {
#pragma unroll
      for (int i = 0; i < 2; ++i) {
        const float* ap =
            pools + (size_t)(rowbase + i * 16 + r16) * C_DIM + d0 + 32;
        pv0[i] = *(const f32x4*)ap;
        pv1[i] = *(const f32x4*)(ap + 4);
      }
    }
#pragma unroll
    for (int j = 0; j < 6; ++j) {
      int col = w * 96 + j * 16 + r16;  // 0..383 = p*128 + m
      size_t boff = (size_t)col * C_DIM + d0;
      s16x8 bh = *(const s16x8*)(pcmh + boff);
      s16x8 bl = *(const s16x8*)(pcml + boff);
#pragma unroll
      for (int i = 0; i < 2; ++i) {
        acc[i][j] = __builtin_amdgcn_mfma_f32_16x16x32_bf16(ah[i], bh, acc[i][j], 0, 0, 0);
        acc[i][j] = __builtin_amdgcn_mfma_f32_16x16x32_bf16(ah[i], bl, acc[i][j], 0, 0, 0);
        acc[i][j] = __builtin_amdgcn_mfma_f32_16x16x32_bf16(al[i], bh, acc[i][j], 0, 0, 0);
      }
    }
  }
#pragma unroll
  for (int i = 0; i < 2; ++i)
#pragma unroll
    for (int j = 0; j < 6; ++j)
#pragma unroll
      for (int r = 0; r < 4; ++r) {
        int row = rowbase + i * 16 + g4 * 4 + r;
        int col = w * 96 + j * 16 + r16;
        int p = col >> 7, m = col & 127;
        xpart[((size_t)(ks * B_DIM + row) * 3 + p) * M_DIM + m] = acc[i][j][r];
      }
}

// ---------------- K4: attention (P=3, H=16, K=8) + pooling head + l2norm, exact fp32
__global__ __launch_bounds__(128) void k4_attn(
    const float* __restrict__ xpart, const float* __restrict__ Wq,
    const float* __restrict__ bq, const float* __restrict__ Wk,
    const float* __restrict__ bk, const float* __restrict__ Wv,
    const float* __restrict__ bv, const float* __restrict__ Wo,
    const float* __restrict__ bo, const float* __restrict__ pk,
    const float* __restrict__ pb, ushort* __restrict__ npool) {
  __shared__ float xs[3 * 128], qa[3 * 128], ka[3 * 128], va[3 * 128], oa[3 * 128], pp[128];
  const int t = threadIdx.x;
  const int b = blockIdx.x;
#pragma unroll
  for (int p = 0; p < 3; ++p) {
    float v = 0.f;
    for (int ks = 0; ks < 16; ++ks)
      v += xpart[((size_t)(ks * B_DIM + b) * 3 + p) * M_DIM + t];
    xs[p * 128 + t] = v;
  }
  __syncthreads();
  float qv[3], kv[3], vv[3];
#pragma unroll
  for (int p = 0; p < 3; ++p) { qv[p] = bq[t]; kv[p] = bk[t]; vv[p] = bv[t]; }
  for (int m = 0; m < 128; ++m) {
    float wq = Wq[m * 128 + t], wk = Wk[m * 128 + t], wv = Wv[m * 128 + t];
#pragma unroll
    for (int p = 0; p < 3; ++p) {
      float xv = xs[p * 128 + m];
      qv[p] += xv * wq;
      kv[p] += xv * wk;
      vv[p] += xv * wv;
    }
  }
#pragma unroll
  for (int p = 0; p < 3; ++p) {
    qa[p * 128 + t] = qv[p];
    ka[p * 128 + t] = kv[p];
    va[p * 128 + t] = vv[p];
  }
  __syncthreads();
  const int h = t >> 3;
  float w[3][3];
#pragma unroll
  for (int p = 0; p < 3; ++p) {
    float s[3];
#pragma unroll
    for (int qq = 0; qq < 3; ++qq) {
      float d = 0.f;
#pragma unroll
      for (int kk = 0; kk < 8; ++kk)
        d += qa[p * 128 + h * 8 + kk] * ka[qq * 128 + h * 8 + kk];
      s[qq] = d / 2.8284271247461903f;
    }
    float mx = fmaxf(s[0], fmaxf(s[1], s[2]));
    float e0 = expf(s[0] - mx), e1 = expf(s[1] - mx), e2 = expf(s[2] - mx);
    float inv = 1.0f / (e0 + e1 + e2);
    w[p][0] = e0 * inv; w[p][1] = e1 * inv; w[p][2] = e2 * inv;
  }
#pragma unroll
  for (int p = 0; p < 3; ++p) {
    float o = w[p][0] * va[0 * 128 + t] + w[p][1] * va[1 * 128 + t] + w[p][2] * va[2 * 128 + t];
    oa[p * 128 + t] = o;
  }
  __syncthreads();
  float pre = 3.0f * bo[t];
#pragma unroll
  for (int p = 0; p < 3; ++p)
    for (int hk = 0; hk < 128; ++hk) pre += oa[p * 128 + hk] * Wo[hk * 128 + t];
  pp[t] = pre;
  __syncthreads();
  if (t < 64) {
    float pe = pb[t];
    for (int m = 0; m < 128; ++m) pe += pp[m] * pk[m * 64 + t];
    float ss = pe * pe;
#pragma unroll
    for (int off = 32; off; off >>= 1) ss += __shfl_xor(ss, off, 64);
    float rs = 1.0f / sqrtf(fmaxf(ss, 1e-12f));
    npool[b * 64 + t] = (ushort)bf16_rne(pe * rs);
  }
}

// ---------------- K4b: normalize card_embeddings rows -> bf16
__global__ __launch_bounds__(256) void k4b_ncard(const float* __restrict__ ce,
                                                 ushort* __restrict__ ncard) {
  const int t = threadIdx.x;
  const int r = blockIdx.x * 4 + (t >> 6);
  const int lane = t & 63;
  float v = ce[(size_t)r * 64 + lane];
  float ss = v * v;
#pragma unroll
  for (int off = 32; off; off >>= 1) ss += __shfl_xor(ss, off, 64);
  float rs = 1.0f / sqrtf(fmaxf(ss, 1e-12f));
  ncard[(size_t)r * 64 + lane] = (ushort)bf16_rne(v * rs);
}

// ---------------- K5: out = (npool @ ncard^T + 1)/2, plain bf16 MFMA, pure-register
__global__ __launch_bounds__(256, 2) void k5_out(const ushort* __restrict__ np_,
                                                 const ushort* __restrict__ nc,
                                                 float* __restrict__ out) {
  const int tid = threadIdx.x;
  const int bt = blockIdx.x, ct = blockIdx.y;
  const int lane = tid & 63, wid = tid >> 6;
  const int wr = wid >> 1, wc = wid & 1;
  const int r16 = lane & 15, g4 = lane >> 4;
  f32x4 acc[4][4];
#pragma unroll
  for (int i = 0; i < 4; ++i)
#pragma unroll
    for (int j = 0; j < 4; ++j) acc[i][j] = (f32x4){0.f, 0.f, 0.f, 0.f};
#pragma unroll
  for (int ks = 0; ks < 2; ++ks) {
    int e0 = ks * 32 + g4 * 8;
    s16x8 af[4], bf_[4];
#pragma unroll
    for (int i = 0; i < 4; ++i)
      af[i] = *(const s16x8*)(np_ + (size_t)(bt * 128 + wr * 64 + i * 16 + r16) * 64 + e0);
#pragma unroll
    for (int j = 0; j < 4; ++j)
      bf_[j] = *(const s16x8*)(nc + (size_t)(ct * 128 + wc * 64 + j * 16 + r16) * 64 + e0);
#pragma unroll
    for (int i = 0; i < 4; ++i)
#pragma unroll
      for (int j = 0; j < 4; ++j)
        acc[i][j] = __builtin_amdgcn_mfma_f32_16x16x32_bf16(af[i], bf_[j], acc[i][j], 0, 0, 0);
  }
#pragma unroll
  for (int i = 0; i < 4; ++i)
#pragma unroll
    for (int j = 0; j < 4; ++j)
#pragma unroll
      for (int r = 0; r < 4; ++r) {
        int row = bt * 128 + wr * 64 + i * 16 + g4 * 4 + r;
        int col = ct * 128 + wc * 64 + j * 16 + r16;
        out[(size_t)row * C_DIM + col] = (acc[i][j][r] + 1.0f) * 0.5f;
      }
}

extern "C" void kernel_launch(void* const* d_in, const int* in_sizes, int n_in,
                              void* d_out, int out_size, void* d_ws, size_t ws_size,
                              hipStream_t stream) {
  const float* pools = (const float*)d_in[0];
  const float* metapaths = (const float*)d_in[1];
  const float* cardemb = (const float*)d_in[2];
  const float* mpk = (const float*)d_in[3];
  const float* mpbias = (const float*)d_in[4];
  const float* Wq = (const float*)d_in[5];
  const float* bq = (const float*)d_in[6];
  const float* Wk = (const float*)d_in[7];
  const float* bk = (const float*)d_in[8];
  const float* Wv = (const float*)d_in[9];
  const float* bv = (const float*)d_in[10];
  const float* Wo = (const float*)d_in[11];
  const float* bo = (const float*)d_in[12];
  const float* pk = (const float*)d_in[13];
  const float* pb = (const float*)d_in[14];
  float* out = (float*)d_out;
  char* ws = (char*)d_ws;

  ushort* pcA = (ushort*)(ws + PCA_OFF);
  float* part = (float*)(ws + PART_OFF);
  ushort* pcmh = (ushort*)(ws + PCMH_OFF);
  ushort* pcml = (ushort*)(ws + PCML_OFF);
  float* xpart = (float*)(ws + XPART_OFF);
  ushort* npool = (ushort*)(ws + NPOOL_OFF);
  ushort* ncard = (ushort*)(ws + NCARD_OFF);

  k1_pathcard<<<dim3(128, 3), dim3(256), 0, stream>>>(cardemb, mpk, mpbias, pcA);
  k2_big<<<dim3(64, 4, 3), dim3(256), 0, stream>>>(metapaths, pcA, part);
  k2b_reduce<<<dim3(3072), dim3(256), 0, stream>>>(part, pcmh, pcml);
  k3_x<<<dim3(32, 16), dim3(256), 0, stream>>>(pools, pcmh, pcml, xpart);
  k4b_ncard<<<dim3(2048), dim3(256), 0, stream>>>(cardemb, ncard);
  k4_attn<<<dim3(1024), dim3(128), 0, stream>>>(xpart, Wq, bq, Wk, bk, Wv, bv, Wo, bo, pk, pb,
                                                npool);
  k5_out<<<dim3(8, 64), dim3(256), 0, stream>>>(npool, ncard, out);
}

// Round 10
// 443.052 us; speedup vs baseline: 1.5483x; 1.5483x over previous
//
#include <hip/hip_runtime.h>
#include <hip/hip_bf16.h>

typedef unsigned int uint;
typedef unsigned short ushort;
typedef float f32x4 __attribute__((ext_vector_type(4)));
typedef short s16x8 __attribute__((ext_vector_type(8)));
typedef int i32x4 __attribute__((ext_vector_type(4)));
typedef uint u32x2 __attribute__((ext_vector_type(2)));

#define C_DIM 8192
#define B_DIM 1024
#define P_DIM 3
#define E_DIM 64
#define M_DIM 128

// workspace layout (bytes)
#define PCA_OFF   0ull                    // path_card hi/lo tile images: 3*256*20480 = 15728640
#define PART_OFF  15728640ull             // K2 partials fp32: 4*3*128*8192*4 = 50331648
#define PCMH_OFF  66060288ull             // pcm hi bf16: 6291456
#define PCML_OFF  72351744ull             // pcm lo bf16: 6291456
#define XPART_OFF PART_OFF                // x partials alias K2 partials (dead by then)
#define NPOOL_OFF 78643200ull             // 1024*64*2
#define NCARD_OFF 78774272ull             // 8192*64*2

__device__ __forceinline__ uint bf16_rne(float f) {
  uint u = __builtin_bit_cast(uint, f);
  return (u + 0x7fffu + ((u >> 16) & 1u)) >> 16;
}
__device__ __forceinline__ float bf16_to_f32(uint b) {
  return __builtin_bit_cast(float, b << 16);
}
// pack 2 f32 -> 2 bf16 (RNE) in one word: low16=a, high16=b
__device__ __forceinline__ uint pk2(float a, float b) {
  float2 t; t.x = a; t.y = b;
  __hip_bfloat162 h2 = __float22bfloat162_rn(t);
  uint r;
  __builtin_memcpy(&r, &h2, 4);
  return r;
}

// ---------------- K1: path_card = silu(ce @ ker + bias), split hi/lo bf16,
// stored as fragment-layout tile images [p][kt=c/32][m*80 + kl*2] (+10240 for lo)
__global__ __launch_bounds__(256) void k1_pathcard(
    const float* __restrict__ cardemb, const float* __restrict__ mpk,
    const float* __restrict__ mpbias, ushort* __restrict__ pcA) {
  __shared__ float ce_l[64 * 68];
  const int tid = threadIdx.x;
  const int cb = blockIdx.x;  // 0..127 (64 c's each)
  const int p  = blockIdx.y;  // 0..2
  for (int r = 0; r < 16; ++r) {
    int i = r * 256 + tid;
    int row = i >> 6, col = i & 63;
    ce_l[row * 68 + col] = cardemb[(size_t)(cb * 64 + row) * 64 + col];
  }
  __syncthreads();
  const int m = tid & 127;
  const int chalf = tid >> 7;
  float kr[64];
#pragma unroll
  for (int e = 0; e < 64; ++e) kr[e] = mpk[(size_t)p * E_DIM * M_DIM + e * M_DIM + m];
  const float bias = mpbias[p * M_DIM + m];
  for (int cl0 = 0; cl0 < 32; ++cl0) {
    int cl = chalf * 32 + cl0;
    float acc = bias;
#pragma unroll
    for (int e = 0; e < 64; ++e) acc += ce_l[cl * 68 + e] * kr[e];
    float s = acc / (1.0f + expf(-acc));  // silu
    uint hb = bf16_rne(s);
    uint lb = bf16_rne(s - bf16_to_f32(hb));
    int c = cb * 64 + cl;
    int kt = c >> 5, kl = c & 31;
    size_t off = ((size_t)(p * 256 + kt) * 20480 + (size_t)m * 80 + (size_t)kl * 2) >> 1;
    pcA[off] = (ushort)hb;
    pcA[off + 5120] = (ushort)lb;  // +10240 bytes
  }
}

// ---------------- K2: partial[q][p] = pcA(128 x 2048) @ metapaths[p](2048 x 8192)
// 3-term bf16 split MFMA, BK=64 (32 steps, one barrier each). A fragments from
// global (L2-resident pcA), issued BEFORE the B prefetch so the auto vmcnt wait
// for A leaves all 32 B(T+2) loads in flight across the barrier (in-order
// retire). All staging via macros on named arrays (no pointer lambdas -> no
// scratch spill). LDS = 2 x 32 KB B dbuf -> 2 blocks/CU.
__global__ __launch_bounds__(256, 2) void k2_big(
    const float* __restrict__ mp, const ushort* __restrict__ pcA,
    float* __restrict__ partial) {
  __shared__ char smem[65536];  // B0[0,32768) B1[32768,65536); each: hi 16K + lo 16K
  const int tid = threadIdx.x;
  int lin = blockIdx.x + 64 * (blockIdx.y + 4 * blockIdx.z);   // 0..767
  int swzb = (lin & 7) * 96 + (lin >> 3);                       // XCD-chunked
  const int dt = swzb & 63, q = (swzb >> 6) & 3, p = swzb >> 8;
  const int lane = tid & 63, wid = tid >> 6;
  const int wr = wid >> 1, wc = wid & 1;
  const int r16 = lane & 15, g4 = lane >> 4;
  const float* mpb = mp + (size_t)p * C_DIM * C_DIM + (size_t)dt * 128;
  const char* pcb = (const char*)pcA + (size_t)(p * 256 + q * 64) * 20480;
  const int sd = tid & 127, skh = tid >> 7;
  const int swsd = (sd ^ (sd >> 3)) & 7;  // write-side 3-bit XOR swizzle

  f32x4 acc[4][4];
#pragma unroll
  for (int i = 0; i < 4; ++i)
#pragma unroll
    for (int j = 0; j < 4; ++j) acc[i][j] = (f32x4){0.f, 0.f, 0.f, 0.f};

  float brA[32], brB[32];
  s16x8 ah[2][4], al[2][4];

// load B k-tile T (64 rows x 128 cols fp32) into named reg array BR
#define LOADB(T, BR)                                                          \
  {                                                                           \
    int c0_ = q * 2048 + (T) * 64;                                            \
    _Pragma("unroll") for (int ii = 0; ii < 4; ++ii) {                        \
      const float* rp_ = mpb + (size_t)(c0_ + ii * 16 + skh * 8) * C_DIM + sd;\
      _Pragma("unroll") for (int j = 0; j < 8; ++j)                           \
          BR[ii * 8 + j] = rp_[(size_t)j * C_DIM];                            \
    }                                                                         \
  }

// convert BR -> bf16 hi/lo, store to LDS buffer BUF (d-row = 128 B, 8 chunks)
#define WRITEB(BR, BUF)                                                       \
  {                                                                           \
    char* bb_ = smem + (BUF) * 32768;                                         \
    _Pragma("unroll") for (int ii = 0; ii < 4; ++ii) {                        \
      uint hw_[4], lw_[4];                                                    \
      _Pragma("unroll") for (int k2 = 0; k2 < 4; ++k2) {                      \
        float v0_ = BR[ii * 8 + k2 * 2], v1_ = BR[ii * 8 + k2 * 2 + 1];       \
        uint h_ = pk2(v0_, v1_);                                              \
        float h0_ = __builtin_bit_cast(float, h_ << 16);                      \
        float h1_ = __builtin_bit_cast(float, h_ & 0xffff0000u);              \
        hw_[k2] = h_;                                                         \
        lw_[k2] = pk2(v0_ - h0_, v1_ - h1_);                                  \
      }                                                                       \
      int off_ = sd * 128 + ((((ii * 2 + skh) ^ swsd)) << 4);                 \
      *(i32x4*)(bb_ + off_) =                                                 \
          (i32x4){(int)hw_[0], (int)hw_[1], (int)hw_[2], (int)hw_[3]};        \
      *(i32x4*)(bb_ + 16384 + off_) =                                         \
          (i32x4){(int)lw_[0], (int)lw_[1], (int)lw_[2], (int)lw_[3]};        \
    }                                                                         \
  }

// A fragments for step T (two k32 subtiles), from global (L2)
#define LOADA(T)                                                              \
  {                                                                           \
    _Pragma("unroll") for (int s = 0; s < 2; ++s) {                           \
      const char* At_ = pcb + (size_t)(2 * (T) + s) * 20480;                  \
      _Pragma("unroll") for (int i = 0; i < 4; ++i) {                         \
        int off_ = (wr * 64 + i * 16 + r16) * 80 + g4 * 16;                   \
        ah[s][i] = *(const s16x8*)(At_ + off_);                               \
        al[s][i] = *(const s16x8*)(At_ + 10240 + off_);                       \
      }                                                                       \
    }                                                                         \
  }

#define MFMAS(BUF)                                                            \
  {                                                                           \
    const char* Bb_ = smem + (BUF) * 32768;                                   \
    _Pragma("unroll") for (int s = 0; s < 2; ++s) {                           \
      _Pragma("unroll") for (int j = 0; j < 4; ++j) {                         \
        int col_ = wc * 64 + j * 16 + r16;                                    \
        int slot_ = (s * 4 + g4) ^ ((col_ ^ (col_ >> 3)) & 7);                \
        int off_ = col_ * 128 + (slot_ << 4);                                 \
        s16x8 bh_ = *(const s16x8*)(Bb_ + off_);                              \
        s16x8 bl_ = *(const s16x8*)(Bb_ + 16384 + off_);                      \
        _Pragma("unroll") for (int i = 0; i < 4; ++i) {                       \
          acc[i][j] =                                                         \
              __builtin_amdgcn_mfma_f32_16x16x32_bf16(ah[s][i], bh_, acc[i][j], 0, 0, 0); \
          acc[i][j] =                                                         \
              __builtin_amdgcn_mfma_f32_16x16x32_bf16(ah[s][i], bl_, acc[i][j], 0, 0, 0); \
          acc[i][j] =                                                         \
              __builtin_amdgcn_mfma_f32_16x16x32_bf16(al[s][i], bh_, acc[i][j], 0, 0, 0); \
        }                                                                     \
      }                                                                       \
    }                                                                         \
  }

  // prologue: B(0)->brA->LDS buf0 (waits only brA's loads; brB's stay in
  // flight), B(1)->brB.
  LOADB(0, brA);
  LOADB(1, brB);
  WRITEB(brA, 0);
  asm volatile("s_waitcnt lgkmcnt(0)" ::: "memory");
  __builtin_amdgcn_s_barrier();
  __builtin_amdgcn_sched_barrier(0);

// step T: A loads FIRST (newest-before-B => waiting A keeps B in flight),
// then issue B(T+2), MFMA from LDS buf[T&1], convert+write B(T+1)->buf[(T+1)&1],
// lgkmcnt(0) only, ONE barrier.
#define K2STEP(T, BRL, BRW)                                                   \
  {                                                                           \
    LOADA(T);                                                                 \
    if ((T) + 2 < 32) LOADB((T) + 2, BRL);                                    \
    MFMAS((T) & 1);                                                           \
    if ((T) < 31) {                                                           \
      WRITEB(BRW, ((T) + 1) & 1);                                             \
      asm volatile("s_waitcnt lgkmcnt(0)" ::: "memory");                      \
      __builtin_amdgcn_s_barrier();                                           \
      __builtin_amdgcn_sched_barrier(0);                                      \
    }                                                                         \
  }

  for (int t2 = 0; t2 < 16; ++t2) {
    int t = 2 * t2;
    K2STEP(t, brA, brB);
    K2STEP(t + 1, brB, brA);
  }
#undef K2STEP
#undef MFMAS
#undef LOADA
#undef WRITEB
#undef LOADB

  float* part = partial + (size_t)(q * 3 + p) * M_DIM * C_DIM + (size_t)dt * 128;
#pragma unroll
  for (int i = 0; i < 4; ++i)
#pragma unroll
    for (int j = 0; j < 4; ++j)
#pragma unroll
      for (int r = 0; r < 4; ++r)
        part[(size_t)(wr * 64 + i * 16 + g4 * 4 + r) * C_DIM + (wc * 64 + j * 16 + r16)] =
            acc[i][j][r];
}

// ---------------- K2b: pcm = sum of 4 q-partials, split to hi/lo bf16 [p][m][d]
__global__ __launch_bounds__(256) void k2b_reduce(const float* __restrict__ p0,
                                                  ushort* __restrict__ oh,
                                                  ushort* __restrict__ ol) {
  size_t i = (size_t)blockIdx.x * 256 + threadIdx.x;  // 786432 threads, 4 elems each
  f32x4 a = *(const f32x4*)(p0 + i * 4);
  f32x4 b = *(const f32x4*)(p0 + 3145728ull + i * 4);
  f32x4 c = *(const f32x4*)(p0 + 6291456ull + i * 4);
  f32x4 d = *(const f32x4*)(p0 + 9437184ull + i * 4);
  f32x4 s = (a + b) + (c + d);
  uint h[2], l[2];
#pragma unroll
  for (int k = 0; k < 2; ++k) {
    float v0 = s[k * 2], v1 = s[k * 2 + 1];
    uint hh = pk2(v0, v1);
    float h0 = __builtin_bit_cast(float, hh << 16);
    float h1 = __builtin_bit_cast(float, hh & 0xffff0000u);
    h[k] = hh;
    l[k] = pk2(v0 - h0, v1 - h1);
  }
  *(u32x2*)(oh + i * 4) = (u32x2){h[0], h[1]};
  *(u32x2*)(ol + i * 4) = (u32x2){l[0], l[1]};
}

// ---------------- K3: x = pools @ pcm^T, 3-term split, pure-register MFMA.
// Grid 32 bt x 16 ks = 512 blocks (2/CU). One-step A (pools) prefetch.
__global__ __launch_bounds__(256, 2) void k3_x(const float* __restrict__ pools,
                                               const ushort* __restrict__ pcmh,
                                               const ushort* __restrict__ pcml,
                                               float* __restrict__ xpart) {
  const int tid = threadIdx.x;
  const int bt = blockIdx.x, ks = blockIdx.y;
  const int lane = tid & 63, w = tid >> 6;
  const int r16 = lane & 15, g4 = lane >> 4;
  const int rowbase = bt * 32;
  f32x4 acc[2][6];
#pragma unroll
  for (int i = 0; i < 2; ++i)
#pragma unroll
    for (int j = 0; j < 6; ++j) acc[i][j] = (f32x4){0.f, 0.f, 0.f, 0.f};

  f32x4 pv0[2], pv1[2];
#pragma unroll
  for (int i = 0; i < 2; ++i) {
    const float* ap = pools + (size_t)(rowbase + i * 16 + r16) * C_DIM + ks * 512 + g4 * 8;
    pv0[i] = *(const f32x4*)ap;
    pv1[i] = *(const f32x4*)(ap + 4);
  }

  for (int t = 0; t < 16; ++t) {
    int d0 = ks * 512 + t * 32 + g4 * 8;
    s16x8 ah[2], al[2];
#pragma unroll
    for (int i = 0; i < 2; ++i) {
      i32x4 hw, lw;
#pragma unroll
      for (int k2 = 0; k2 < 4; ++k2) {
        float x0 = (k2 < 2) ? pv0[i][k2 * 2] : pv1[i][(k2 - 2) * 2];
        float x1 = (k2 < 2) ? pv0[i][k2 * 2 + 1] : pv1[i][(k2 - 2) * 2 + 1];
        uint h = pk2(x0, x1);
        float h0 = __builtin_bit_cast(float, h << 16);
        float h1 = __builtin_bit_cast(float, h & 0xffff0000u);
        hw[k2] = (int)h;
        lw[k2] = (int)pk2(x0 - h0, x1 - h1);
      }
      ah[i] = __builtin_bit_cast(s16x8, hw);
      al[i] = __builtin_bit_cast(s16x8, lw);
    }
    if (t < 15) {
#pragma unroll
      for (int i = 0; i < 2; ++i) {
        const float* ap =
            pools + (size_t)(rowbase + i * 16 + r16) * C_DIM + d0 + 32;
        pv0[i] = *(const f32x4*)ap;
        pv1[i] = *(const f32x4*)(ap + 4);
      }
    }
#pragma unroll
    for (int j = 0; j < 6; ++j) {
      int col = w * 96 + j * 16 + r16;  // 0..383 = p*128 + m
      size_t boff = (size_t)col * C_DIM + d0;
      s16x8 bh = *(const s16x8*)(pcmh + boff);
      s16x8 bl = *(const s16x8*)(pcml + boff);
#pragma unroll
      for (int i = 0; i < 2; ++i) {
        acc[i][j] = __builtin_amdgcn_mfma_f32_16x16x32_bf16(ah[i], bh, acc[i][j], 0, 0, 0);
        acc[i][j] = __builtin_amdgcn_mfma_f32_16x16x32_bf16(ah[i], bl, acc[i][j], 0, 0, 0);
        acc[i][j] = __builtin_amdgcn_mfma_f32_16x16x32_bf16(al[i], bh, acc[i][j], 0, 0, 0);
      }
    }
  }
#pragma unroll
  for (int i = 0; i < 2; ++i)
#pragma unroll
    for (int j = 0; j < 6; ++j)
#pragma unroll
      for (int r = 0; r < 4; ++r) {
        int row = rowbase + i * 16 + g4 * 4 + r;
        int col = w * 96 + j * 16 + r16;
        int p = col >> 7, m = col & 127;
        xpart[((size_t)(ks * B_DIM + row) * 3 + p) * M_DIM + m] = acc[i][j][r];
      }
}

// ---------------- K4: attention (P=3, H=16, K=8) + pooling head + l2norm, exact fp32
__global__ __launch_bounds__(128) void k4_attn(
    const float* __restrict__ xpart, const float* __restrict__ Wq,
    const float* __restrict__ bq, const float* __restrict__ Wk,
    const float* __restrict__ bk, const float* __restrict__ Wv,
    const float* __restrict__ bv, const float* __restrict__ Wo,
    const float* __restrict__ bo, const float* __restrict__ pk,
    const float* __restrict__ pb, ushort* __restrict__ npool) {
  __shared__ float xs[3 * 128], qa[3 * 128], ka[3 * 128], va[3 * 128], oa[3 * 128], pp[128];
  const int t = threadIdx.x;
  const int b = blockIdx.x;
#pragma unroll
  for (int p = 0; p < 3; ++p) {
    float v = 0.f;
    for (int ks = 0; ks < 16; ++ks)
      v += xpart[((size_t)(ks * B_DIM + b) * 3 + p) * M_DIM + t];
    xs[p * 128 + t] = v;
  }
  __syncthreads();
  float qv[3], kv[3], vv[3];
#pragma unroll
  for (int p = 0; p < 3; ++p) { qv[p] = bq[t]; kv[p] = bk[t]; vv[p] = bv[t]; }
  for (int m = 0; m < 128; ++m) {
    float wq = Wq[m * 128 + t], wk = Wk[m * 128 + t], wv = Wv[m * 128 + t];
#pragma unroll
    for (int p = 0; p < 3; ++p) {
      float xv = xs[p * 128 + m];
      qv[p] += xv * wq;
      kv[p] += xv * wk;
      vv[p] += xv * wv;
    }
  }
#pragma unroll
  for (int p = 0; p < 3; ++p) {
    qa[p * 128 + t] = qv[p];
    ka[p * 128 + t] = kv[p];
    va[p * 128 + t] = vv[p];
  }
  __syncthreads();
  const int h = t >> 3;
  float w[3][3];
#pragma unroll
  for (int p = 0; p < 3; ++p) {
    float s[3];
#pragma unroll
    for (int qq = 0; qq < 3; ++qq) {
      float d = 0.f;
#pragma unroll
      for (int kk = 0; kk < 8; ++kk)
        d += qa[p * 128 + h * 8 + kk] * ka[qq * 128 + h * 8 + kk];
      s[qq] = d / 2.8284271247461903f;
    }
    float mx = fmaxf(s[0], fmaxf(s[1], s[2]));
    float e0 = expf(s[0] - mx), e1 = expf(s[1] - mx), e2 = expf(s[2] - mx);
    float inv = 1.0f / (e0 + e1 + e2);
    w[p][0] = e0 * inv; w[p][1] = e1 * inv; w[p][2] = e2 * inv;
  }
#pragma unroll
  for (int p = 0; p < 3; ++p) {
    float o = w[p][0] * va[0 * 128 + t] + w[p][1] * va[1 * 128 + t] + w[p][2] * va[2 * 128 + t];
    oa[p * 128 + t] = o;
  }
  __syncthreads();
  float pre = 3.0f * bo[t];
#pragma unroll
  for (int p = 0; p < 3; ++p)
    for (int hk = 0; hk < 128; ++hk) pre += oa[p * 128 + hk] * Wo[hk * 128 + t];
  pp[t] = pre;
  __syncthreads();
  if (t < 64) {
    float pe = pb[t];
    for (int m = 0; m < 128; ++m) pe += pp[m] * pk[m * 64 + t];
    float ss = pe * pe;
#pragma unroll
    for (int off = 32; off; off >>= 1) ss += __shfl_xor(ss, off, 64);
    float rs = 1.0f / sqrtf(fmaxf(ss, 1e-12f));
    npool[b * 64 + t] = (ushort)bf16_rne(pe * rs);
  }
}

// ---------------- K4b: normalize card_embeddings rows -> bf16
__global__ __launch_bounds__(256) void k4b_ncard(const float* __restrict__ ce,
                                                 ushort* __restrict__ ncard) {
  const int t = threadIdx.x;
  const int r = blockIdx.x * 4 + (t >> 6);
  const int lane = t & 63;
  float v = ce[(size_t)r * 64 + lane];
  float ss = v * v;
#pragma unroll
  for (int off = 32; off; off >>= 1) ss += __shfl_xor(ss, off, 64);
  float rs = 1.0f / sqrtf(fmaxf(ss, 1e-12f));
  ncard[(size_t)r * 64 + lane] = (ushort)bf16_rne(v * rs);
}

// ---------------- K5: out = (npool @ ncard^T + 1)/2, plain bf16 MFMA, pure-register
__global__ __launch_bounds__(256, 2) void k5_out(const ushort* __restrict__ np_,
                                                 const ushort* __restrict__ nc,
                                                 float* __restrict__ out) {
  const int tid = threadIdx.x;
  const int bt = blockIdx.x, ct = blockIdx.y;
  const int lane = tid & 63, wid = tid >> 6;
  const int wr = wid >> 1, wc = wid & 1;
  const int r16 = lane & 15, g4 = lane >> 4;
  f32x4 acc[4][4];
#pragma unroll
  for (int i = 0; i < 4; ++i)
#pragma unroll
    for (int j = 0; j < 4; ++j) acc[i][j] = (f32x4){0.f, 0.f, 0.f, 0.f};
#pragma unroll
  for (int ks = 0; ks < 2; ++ks) {
    int e0 = ks * 32 + g4 * 8;
    s16x8 af[4], bf_[4];
#pragma unroll
    for (int i = 0; i < 4; ++i)
      af[i] = *(const s16x8*)(np_ + (size_t)(bt * 128 + wr * 64 + i * 16 + r16) * 64 + e0);
#pragma unroll
    for (int j = 0; j < 4; ++j)
      bf_[j] = *(const s16x8*)(nc + (size_t)(ct * 128 + wc * 64 + j * 16 + r16) * 64 + e0);
#pragma unroll
    for (int i = 0; i < 4; ++i)
#pragma unroll
      for (int j = 0; j < 4; ++j)
        acc[i][j] = __builtin_amdgcn_mfma_f32_16x16x32_bf16(af[i], bf_[j], acc[i][j], 0, 0, 0);
  }
#pragma unroll
  for (int i = 0; i < 4; ++i)
#pragma unroll
    for (int j = 0; j < 4; ++j)
#pragma unroll
      for (int r = 0; r < 4; ++r) {
        int row = bt * 128 + wr * 64 + i * 16 + g4 * 4 + r;
        int col = ct * 128 + wc * 64 + j * 16 + r16;
        out[(size_t)row * C_DIM + col] = (acc[i][j][r] + 1.0f) * 0.5f;
      }
}

extern "C" void kernel_launch(void* const* d_in, const int* in_sizes, int n_in,
                              void* d_out, int out_size, void* d_ws, size_t ws_size,
                              hipStream_t stream) {
  const float* pools = (const float*)d_in[0];
  const float* metapaths = (const float*)d_in[1];
  const float* cardemb = (const float*)d_in[2];
  const float* mpk = (const float*)d_in[3];
  const float* mpbias = (const float*)d_in[4];
  const float* Wq = (const float*)d_in[5];
  const float* bq = (const float*)d_in[6];
  const float* Wk = (const float*)d_in[7];
  const float* bk = (const float*)d_in[8];
  const float* Wv = (const float*)d_in[9];
  const float* bv = (const float*)d_in[10];
  const float* Wo = (const float*)d_in[11];
  const float* bo = (const float*)d_in[12];
  const float* pk = (const float*)d_in[13];
  const float* pb = (const float*)d_in[14];
  float* out = (float*)d_out;
  char* ws = (char*)d_ws;

  ushort* pcA = (ushort*)(ws + PCA_OFF);
  float* part = (float*)(ws + PART_OFF);
  ushort* pcmh = (ushort*)(ws + PCMH_OFF);
  ushort* pcml = (ushort*)(ws + PCML_OFF);
  float* xpart = (float*)(ws + XPART_OFF);
  ushort* npool = (ushort*)(ws + NPOOL_OFF);
  ushort* ncard = (ushort*)(ws + NCARD_OFF);

  k1_pathcard<<<dim3(128, 3), dim3(256), 0, stream>>>(cardemb, mpk, mpbias, pcA);
  k2_big<<<dim3(64, 4, 3), dim3(256), 0, stream>>>(metapaths, pcA, part);
  k2b_reduce<<<dim3(3072), dim3(256), 0, stream>>>(part, pcmh, pcml);
  k3_x<<<dim3(32, 16), dim3(256), 0, stream>>>(pools, pcmh, pcml, xpart);
  k4b_ncard<<<dim3(2048), dim3(256), 0, stream>>>(cardemb, ncard);
  k4_attn<<<dim3(1024), dim3(128), 0, stream>>>(xpart, Wq, bq, Wk, bk, Wv, bv, Wo, bo, pk, pb,
                                                npool);
  k5_out<<<dim3(8, 64), dim3(256), 0, stream>>>(npool, ncard, out);
}

// Round 12
// 353.388 us; speedup vs baseline: 1.9411x; 1.2537x over previous
//
#include <hip/hip_runtime.h>
#include <hip/hip_bf16.h>

typedef unsigned int uint;
typedef unsigned short ushort;
typedef float f32x4 __attribute__((ext_vector_type(4)));
typedef short s16x8 __attribute__((ext_vector_type(8)));
typedef int i32x4 __attribute__((ext_vector_type(4)));
typedef uint u32x2 __attribute__((ext_vector_type(2)));

#define C_DIM 8192
#define B_DIM 1024
#define P_DIM 3
#define E_DIM 64
#define M_DIM 128

// workspace layout (bytes)
#define PCA_OFF   0ull                    // path_card hi/lo tile images: 3*256*20480 = 15728640
#define PART_OFF  15728640ull             // K2 partials fp32: 4*3*128*8192*4 = 50331648
#define PCMH_OFF  66060288ull             // pcm hi bf16: 6291456
#define PCML_OFF  72351744ull             // pcm lo bf16: 6291456
#define XPART_OFF PART_OFF                // x partials alias K2 partials (dead by then)
#define NPOOL_OFF 78643200ull             // 1024*64*2
#define NCARD_OFF 78774272ull             // 8192*64*2

__device__ __forceinline__ uint bf16_rne(float f) {
  uint u = __builtin_bit_cast(uint, f);
  return (u + 0x7fffu + ((u >> 16) & 1u)) >> 16;
}
__device__ __forceinline__ float bf16_to_f32(uint b) {
  return __builtin_bit_cast(float, b << 16);
}
// pack 2 f32 -> 2 bf16 (RNE) in one word: low16=a, high16=b
__device__ __forceinline__ uint pk2(float a, float b) {
  float2 t; t.x = a; t.y = b;
  __hip_bfloat162 h2 = __float22bfloat162_rn(t);
  uint r;
  __builtin_memcpy(&r, &h2, 4);
  return r;
}

// ---------------- K1: path_card = silu(ce @ ker + bias), split hi/lo bf16,
// stored as fragment-layout tile images [p][kt=c/32][m*80 + kl*2] (+10240 for lo)
__global__ __launch_bounds__(256) void k1_pathcard(
    const float* __restrict__ cardemb, const float* __restrict__ mpk,
    const float* __restrict__ mpbias, ushort* __restrict__ pcA) {
  __shared__ float ce_l[64 * 68];
  const int tid = threadIdx.x;
  const int cb = blockIdx.x;  // 0..127 (64 c's each)
  const int p  = blockIdx.y;  // 0..2
  for (int r = 0; r < 16; ++r) {
    int i = r * 256 + tid;
    int row = i >> 6, col = i & 63;
    ce_l[row * 68 + col] = cardemb[(size_t)(cb * 64 + row) * 64 + col];
  }
  __syncthreads();
  const int m = tid & 127;
  const int chalf = tid >> 7;
  float kr[64];
#pragma unroll
  for (int e = 0; e < 64; ++e) kr[e] = mpk[(size_t)p * E_DIM * M_DIM + e * M_DIM + m];
  const float bias = mpbias[p * M_DIM + m];
  for (int cl0 = 0; cl0 < 32; ++cl0) {
    int cl = chalf * 32 + cl0;
    float acc = bias;
#pragma unroll
    for (int e = 0; e < 64; ++e) acc += ce_l[cl * 68 + e] * kr[e];
    float s = acc / (1.0f + expf(-acc));  // silu
    uint hb = bf16_rne(s);
    uint lb = bf16_rne(s - bf16_to_f32(hb));
    int c = cb * 64 + cl;
    int kt = c >> 5, kl = c & 31;
    size_t off = ((size_t)(p * 256 + kt) * 20480 + (size_t)m * 80 + (size_t)kl * 2) >> 1;
    pcA[off] = (ushort)hb;
    pcA[off + 5120] = (ushort)lb;  // +10240 bytes
  }
}

// ---------------- K2: partial[q][p] = pcA(128 x 2048) @ metapaths[p](2048 x 8192)
// 3-term bf16 split MFMA (R8 geometry: 256 thr / 4 waves, A direct from global
// L2-resident pcA, B 2-reg-buf -> XOR-swizzled LDS dbuf, one barrier/step,
// 32 KB LDS -> 3 blocks/CU). ONE change vs R8: within each step the A-fragment
// global loads are issued BEFORE loadB(T+2), so the compiler's implicit wait
// for A is a counted vmcnt(16) and the 16 B(T+2) loads stay in flight across
// the barrier (in-order vmcnt retire). Macros on named arrays (no lambdas).
__global__ __launch_bounds__(256, 3) void k2_big(
    const float* __restrict__ mp, const ushort* __restrict__ pcA,
    float* __restrict__ partial) {
  __shared__ char smem[32768];  // B0[0,16384) B1[16384,32768); each: hi 8K + lo 8K
  const int tid = threadIdx.x;
  int lin = blockIdx.x + 64 * (blockIdx.y + 4 * blockIdx.z);   // 0..767
  int swz = (lin & 7) * 96 + (lin >> 3);                        // XCD-chunked
  const int dt = swz & 63, q = (swz >> 6) & 3, p = swz >> 8;
  const int lane = tid & 63, wid = tid >> 6;
  const int wr = wid >> 1, wc = wid & 1;
  const int r16 = lane & 15, g4 = lane >> 4;
  const float* mpb = mp + (size_t)p * C_DIM * C_DIM + (size_t)dt * 128;
  const char* pcb = (const char*)pcA + (size_t)(p * 256 + q * 64) * 20480;
  const int sd = tid & 127, skh = tid >> 7;
  const int fc = ((sd ^ (sd >> 2)) & 3) << 4;    // write-side XOR swizzle
  const int fr = ((r16 ^ (r16 >> 2)) & 3) << 4;  // read-side XOR swizzle

  f32x4 acc[4][4];
#pragma unroll
  for (int i = 0; i < 4; ++i)
#pragma unroll
    for (int j = 0; j < 4; ++j) acc[i][j] = (f32x4){0.f, 0.f, 0.f, 0.f};

  float brA[16], brB[16];
  s16x8 ah[4], al[4];

// A fragments for step T, from global (L2-hit pcA tile image)
#define LOADA(T)                                                              \
  {                                                                           \
    const char* At_ = pcb + (size_t)(T) * 20480;                              \
    _Pragma("unroll") for (int i = 0; i < 4; ++i) {                           \
      int offa_ = (wr * 64 + i * 16 + r16) * 80 + g4 * 16;                    \
      ah[i] = *(const s16x8*)(At_ + offa_);                                   \
      al[i] = *(const s16x8*)(At_ + 10240 + offa_);                           \
    }                                                                         \
  }

// load B k-tile T (32 rows x 128 cols fp32) into named reg array BR
#define LOADB(T, BR)                                                          \
  {                                                                           \
    int c0_ = q * 2048 + (T) * 32;                                            \
    _Pragma("unroll") for (int ii = 0; ii < 2; ++ii) {                        \
      const float* rp_ = mpb + (size_t)(c0_ + ii * 16 + skh * 8) * C_DIM + sd;\
      _Pragma("unroll") for (int j = 0; j < 8; ++j)                           \
          BR[ii * 8 + j] = rp_[(size_t)j * C_DIM];                            \
    }                                                                         \
  }

// convert BR -> bf16 hi/lo, store to LDS buffer BUF
#define WRITEB(BR, BUF)                                                       \
  {                                                                           \
    char* bb_ = smem + (BUF) * 16384;                                         \
    _Pragma("unroll") for (int ii = 0; ii < 2; ++ii) {                        \
      uint hw_[4], lw_[4];                                                    \
      _Pragma("unroll") for (int k2 = 0; k2 < 4; ++k2) {                      \
        float v0_ = BR[ii * 8 + k2 * 2], v1_ = BR[ii * 8 + k2 * 2 + 1];       \
        uint h_ = pk2(v0_, v1_);                                              \
        float h0_ = __builtin_bit_cast(float, h_ << 16);                      \
        float h1_ = __builtin_bit_cast(float, h_ & 0xffff0000u);              \
        hw_[k2] = h_;                                                         \
        lw_[k2] = pk2(v0_ - h0_, v1_ - h1_);                                  \
      }                                                                       \
      int off_ = sd * 64 + ((((ii * 2 + skh) << 4)) ^ fc);                    \
      *(i32x4*)(bb_ + off_) =                                                 \
          (i32x4){(int)hw_[0], (int)hw_[1], (int)hw_[2], (int)hw_[3]};        \
      *(i32x4*)(bb_ + 8192 + off_) =                                          \
          (i32x4){(int)lw_[0], (int)lw_[1], (int)lw_[2], (int)lw_[3]};        \
    }                                                                         \
  }

// B ds_reads + 48 MFMAs from LDS buffer BUF (uses ah/al loaded by LOADA)
#define MFMAB(BUF)                                                            \
  {                                                                           \
    const char* Bb_ = smem + (BUF) * 16384;                                   \
    _Pragma("unroll") for (int j = 0; j < 4; ++j) {                           \
      int offb_ = (wc * 64 + j * 16 + r16) * 64 + ((g4 << 4) ^ fr);           \
      s16x8 bh_ = *(const s16x8*)(Bb_ + offb_);                               \
      s16x8 bl_ = *(const s16x8*)(Bb_ + 8192 + offb_);                        \
      _Pragma("unroll") for (int i = 0; i < 4; ++i) {                         \
        acc[i][j] =                                                           \
            __builtin_amdgcn_mfma_f32_16x16x32_bf16(ah[i], bh_, acc[i][j], 0, 0, 0); \
        acc[i][j] =                                                           \
            __builtin_amdgcn_mfma_f32_16x16x32_bf16(ah[i], bl_, acc[i][j], 0, 0, 0); \
        acc[i][j] =                                                           \
            __builtin_amdgcn_mfma_f32_16x16x32_bf16(al[i], bh_, acc[i][j], 0, 0, 0); \
      }                                                                       \
    }                                                                         \
  }

  // prologue: B(0)->brA->LDS buf0; B(1)->brB (stays in flight)
  LOADB(0, brA);
  LOADB(1, brB);
  WRITEB(brA, 0);
  asm volatile("s_waitcnt lgkmcnt(0)" ::: "memory");
  __builtin_amdgcn_s_barrier();
  __builtin_amdgcn_sched_barrier(0);

// step T: A fragments FIRST (older), then issue B(T+2) (younger) -> the
// compiler's wait for ah/al is vmcnt(16), leaving B(T+2) in flight across the
// barrier. MFMA from LDS buf[T&1]; convert+write B(T+1)->buf[(T+1)&1];
// lgkmcnt(0) only; ONE barrier.
#define K2S(T, BRL, BRW, TAIL)                                                \
  {                                                                           \
    LOADA(T);                                                                 \
    asm volatile("" ::: "memory");                                            \
    if ((T) < 62) LOADB((T) + 2, BRL);                                        \
    MFMAB((T) & 1);                                                           \
    if (!(TAIL)) {                                                            \
      WRITEB(BRW, ((T) + 1) & 1);                                             \
      asm volatile("s_waitcnt lgkmcnt(0)" ::: "memory");                      \
      __builtin_amdgcn_s_barrier();                                           \
      __builtin_amdgcn_sched_barrier(0);                                      \
    }                                                                         \
  }

  for (int t2 = 0; t2 < 32; ++t2) {
    int t = 2 * t2;
    K2S(t, brA, brB, false);
    K2S(t + 1, brB, brA, (t2 == 31));
  }
#undef K2S
#undef MFMAB
#undef WRITEB
#undef LOADB
#undef LOADA

  float* part = partial + (size_t)(q * 3 + p) * M_DIM * C_DIM + (size_t)dt * 128;
#pragma unroll
  for (int i = 0; i < 4; ++i)
#pragma unroll
    for (int j = 0; j < 4; ++j)
#pragma unroll
      for (int r = 0; r < 4; ++r)
        part[(size_t)(wr * 64 + i * 16 + g4 * 4 + r) * C_DIM + (wc * 64 + j * 16 + r16)] =
            acc[i][j][r];
}

// ---------------- K2b: pcm = sum of 4 q-partials, split to hi/lo bf16 [p][m][d]
__global__ __launch_bounds__(256) void k2b_reduce(const float* __restrict__ p0,
                                                  ushort* __restrict__ oh,
                                                  ushort* __restrict__ ol) {
  size_t i = (size_t)blockIdx.x * 256 + threadIdx.x;  // 786432 threads, 4 elems each
  f32x4 a = *(const f32x4*)(p0 + i * 4);
  f32x4 b = *(const f32x4*)(p0 + 3145728ull + i * 4);
  f32x4 c = *(const f32x4*)(p0 + 6291456ull + i * 4);
  f32x4 d = *(const f32x4*)(p0 + 9437184ull + i * 4);
  f32x4 s = (a + b) + (c + d);
  uint h[2], l[2];
#pragma unroll
  for (int k = 0; k < 2; ++k) {
    float v0 = s[k * 2], v1 = s[k * 2 + 1];
    uint hh = pk2(v0, v1);
    float h0 = __builtin_bit_cast(float, hh << 16);
    float h1 = __builtin_bit_cast(float, hh & 0xffff0000u);
    h[k] = hh;
    l[k] = pk2(v0 - h0, v1 - h1);
  }
  *(u32x2*)(oh + i * 4) = (u32x2){h[0], h[1]};
  *(u32x2*)(ol + i * 4) = (u32x2){l[0], l[1]};
}

// ---------------- K3: x = pools @ pcm^T, 3-term split, pure-register MFMA.
// Grid 32 bt x 16 ks = 512 blocks (2/CU). One-step A (pools) prefetch.
__global__ __launch_bounds__(256, 2) void k3_x(const float* __restrict__ pools,
                                               const ushort* __restrict__ pcmh,
                                               const ushort* __restrict__ pcml,
                                               float* __restrict__ xpart) {
  const int tid = threadIdx.x;
  const int bt = blockIdx.x, ks = blockIdx.y;
  const int lane = tid & 63, w = tid >> 6;
  const int r16 = lane & 15, g4 = lane >> 4;
  const int rowbase = bt * 32;
  f32x4 acc[2][6];
#pragma unroll
  for (int i = 0; i < 2; ++i)
#pragma unroll
    for (int j = 0; j < 6; ++j) acc[i][j] = (f32x4){0.f, 0.f, 0.f, 0.f};

  f32x4 pv0[2], pv1[2];
#pragma unroll
  for (int i = 0; i < 2; ++i) {
    const float* ap = pools + (size_t)(rowbase + i * 16 + r16) * C_DIM + ks * 512 + g4 * 8;
    pv0[i] = *(const f32x4*)ap;
    pv1[i] = *(const f32x4*)(ap + 4);
  }

  for (int t = 0; t < 16; ++t) {
    int d0 = ks * 512 + t * 32 + g4 * 8;
    s16x8 ah[2], al[2];
#pragma unroll
    for (int i = 0; i < 2; ++i) {
      i32x4 hw, lw;
#pragma unroll
      for (int k2 = 0; k2 < 4; ++k2) {
        float x0 = (k2 < 2) ? pv0[i][k2 * 2] : pv1[i][(k2 - 2) * 2];
        float x1 = (k2 < 2) ? pv0[i][k2 * 2 + 1] : pv1[i][(k2 - 2) * 2 + 1];
        uint h = pk2(x0, x1);
        float h0 = __builtin_bit_cast(float, h << 16);
        float h1 = __builtin_bit_cast(float, h & 0xffff0000u);
        hw[k2] = (int)h;
        lw[k2] = (int)pk2(x0 - h0, x1 - h1);
      }
      ah[i] = __builtin_bit_cast(s16x8, hw);
      al[i] = __builtin_bit_cast(s16x8, lw);
    }
    if (t < 15) {
#pragma unroll
      for (int i = 0; i < 2; ++i) {
        const float* ap =
            pools + (size_t)(rowbase + i * 16 + r16) * C_DIM + d0 + 32;
        pv0[i] = *(const f32x4*)ap;
        pv1[i] = *(const f32x4*)(ap + 4);
      }
    }
#pragma unroll
    for (int j = 0; j < 6; ++j) {
      int col = w * 96 + j * 16 + r16;  // 0..383 = p*128 + m
      size_t boff = (size_t)col * C_DIM + d0;
      s16x8 bh = *(const s16x8*)(pcmh + boff);
      s16x8 bl = *(const s16x8*)(pcml + boff);
#pragma unroll
      for (int i = 0; i < 2; ++i) {
        acc[i][j] = __builtin_amdgcn_mfma_f32_16x16x32_bf16(ah[i], bh, acc[i][j], 0, 0, 0);
        acc[i][j] = __builtin_amdgcn_mfma_f32_16x16x32_bf16(ah[i], bl, acc[i][j], 0, 0, 0);
        acc[i][j] = __builtin_amdgcn_mfma_f32_16x16x32_bf16(al[i], bh, acc[i][j], 0, 0, 0);
      }
    }
  }
#pragma unroll
  for (int i = 0; i < 2; ++i)
#pragma unroll
    for (int j = 0; j < 6; ++j)
#pragma unroll
      for (int r = 0; r < 4; ++r) {
        int row = rowbase + i * 16 + g4 * 4 + r;
        int col = w * 96 + j * 16 + r16;
        int p = col >> 7, m = col & 127;
        xpart[((size_t)(ks * B_DIM + row) * 3 + p) * M_DIM + m] = acc[i][j][r];
      }
}

// ---------------- K4: attention (P=3, H=16, K=8) + pooling head + l2norm, exact fp32
__global__ __launch_bounds__(128) void k4_attn(
    const float* __restrict__ xpart, const float* __restrict__ Wq,
    const float* __restrict__ bq, const float* __restrict__ Wk,
    const float* __restrict__ bk, const float* __restrict__ Wv,
    const float* __restrict__ bv, const float* __restrict__ Wo,
    const float* __restrict__ bo, const float* __restrict__ pk,
    const float* __restrict__ pb, ushort* __restrict__ npool) {
  __shared__ float xs[3 * 128], qa[3 * 128], ka[3 * 128], va[3 * 128], oa[3 * 128], pp[128];
  const int t = threadIdx.x;
  const int b = blockIdx.x;
#pragma unroll
  for (int p = 0; p < 3; ++p) {
    float v = 0.f;
    for (int ks = 0; ks < 16; ++ks)
      v += xpart[((size_t)(ks * B_DIM + b) * 3 + p) * M_DIM + t];
    xs[p * 128 + t] = v;
  }
  __syncthreads();
  float qv[3], kv[3], vv[3];
#pragma unroll
  for (int p = 0; p < 3; ++p) { qv[p] = bq[t]; kv[p] = bk[t]; vv[p] = bv[t]; }
  for (int m = 0; m < 128; ++m) {
    float wq = Wq[m * 128 + t], wk = Wk[m * 128 + t], wv = Wv[m * 128 + t];
#pragma unroll
    for (int p = 0; p < 3; ++p) {
      float xv = xs[p * 128 + m];
      qv[p] += xv * wq;
      kv[p] += xv * wk;
      vv[p] += xv * wv;
    }
  }
#pragma unroll
  for (int p = 0; p < 3; ++p) {
    qa[p * 128 + t] = qv[p];
    ka[p * 128 + t] = kv[p];
    va[p * 128 + t] = vv[p];
  }
  __syncthreads();
  const int h = t >> 3;
  float w[3][3];
#pragma unroll
  for (int p = 0; p < 3; ++p) {
    float s[3];
#pragma unroll
    for (int qq = 0; qq < 3; ++qq) {
      float d = 0.f;
#pragma unroll
      for (int kk = 0; kk < 8; ++kk)
        d += qa[p * 128 + h * 8 + kk] * ka[qq * 128 + h * 8 + kk];
      s[qq] = d / 2.8284271247461903f;
    }
    float mx = fmaxf(s[0], fmaxf(s[1], s[2]));
    float e0 = expf(s[0] - mx), e1 = expf(s[1] - mx), e2 = expf(s[2] - mx);
    float inv = 1.0f / (e0 + e1 + e2);
    w[p][0] = e0 * inv; w[p][1] = e1 * inv; w[p][2] = e2 * inv;
  }
#pragma unroll
  for (int p = 0; p < 3; ++p) {
    float o = w[p][0] * va[0 * 128 + t] + w[p][1] * va[1 * 128 + t] + w[p][2] * va[2 * 128 + t];
    oa[p * 128 + t] = o;
  }
  __syncthreads();
  float pre = 3.0f * bo[t];
#pragma unroll
  for (int p = 0; p < 3; ++p)
    for (int hk = 0; hk < 128; ++hk) pre += oa[p * 128 + hk] * Wo[hk * 128 + t];
  pp[t] = pre;
  __syncthreads();
  if (t < 64) {
    float pe = pb[t];
    for (int m = 0; m < 128; ++m) pe += pp[m] * pk[m * 64 + t];
    float ss = pe * pe;
#pragma unroll
    for (int off = 32; off; off >>= 1) ss += __shfl_xor(ss, off, 64);
    float rs = 1.0f / sqrtf(fmaxf(ss, 1e-12f));
    npool[b * 64 + t] = (ushort)bf16_rne(pe * rs);
  }
}

// ---------------- K4b: normalize card_embeddings rows -> bf16
__global__ __launch_bounds__(256) void k4b_ncard(const float* __restrict__ ce,
                                                 ushort* __restrict__ ncard) {
  const int t = threadIdx.x;
  const int r = blockIdx.x * 4 + (t >> 6);
  const int lane = t & 63;
  float v = ce[(size_t)r * 64 + lane];
  float ss = v * v;
#pragma unroll
  for (int off = 32; off; off >>= 1) ss += __shfl_xor(ss, off, 64);
  float rs = 1.0f / sqrtf(fmaxf(ss, 1e-12f));
  ncard[(size_t)r * 64 + lane] = (ushort)bf16_rne(v * rs);
}

// ---------------- K5: out = (npool @ ncard^T + 1)/2, plain bf16 MFMA, pure-register
__global__ __launch_bounds__(256, 2) void k5_out(const ushort* __restrict__ np_,
                                                 const ushort* __restrict__ nc,
                                                 float* __restrict__ out) {
  const int tid = threadIdx.x;
  const int bt = blockIdx.x, ct = blockIdx.y;
  const int lane = tid & 63, wid = tid >> 6;
  const int wr = wid >> 1, wc = wid & 1;
  const int r16 = lane & 15, g4 = lane >> 4;
  f32x4 acc[4][4];
#pragma unroll
  for (int i = 0; i < 4; ++i)
#pragma unroll
    for (int j = 0; j < 4; ++j) acc[i][j] = (f32x4){0.f, 0.f, 0.f, 0.f};
#pragma unroll
  for (int ks = 0; ks < 2; ++ks) {
    int e0 = ks * 32 + g4 * 8;
    s16x8 af[4], bf_[4];
#pragma unroll
    for (int i = 0; i < 4; ++i)
      af[i] = *(const s16x8*)(np_ + (size_t)(bt * 128 + wr * 64 + i * 16 + r16) * 64 + e0);
#pragma unroll
    for (int j = 0; j < 4; ++j)
      bf_[j] = *(const s16x8*)(nc + (size_t)(ct * 128 + wc * 64 + j * 16 + r16) * 64 + e0);
#pragma unroll
    for (int i = 0; i < 4; ++i)
#pragma unroll
      for (int j = 0; j < 4; ++j)
        acc[i][j] = __builtin_amdgcn_mfma_f32_16x16x32_bf16(af[i], bf_[j], acc[i][j], 0, 0, 0);
  }
#pragma unroll
  for (int i = 0; i < 4; ++i)
#pragma unroll
    for (int j = 0; j < 4; ++j)
#pragma unroll
      for (int r = 0; r < 4; ++r) {
        int row = bt * 128 + wr * 64 + i * 16 + g4 * 4 + r;
        int col = ct * 128 + wc * 64 + j * 16 + r16;
        out[(size_t)row * C_DIM + col] = (acc[i][j][r] + 1.0f) * 0.5f;
      }
}

extern "C" void kernel_launch(void* const* d_in, const int* in_sizes, int n_in,
                              void* d_out, int out_size, void* d_ws, size_t ws_size,
                              hipStream_t stream) {
  const float* pools = (const float*)d_in[0];
  const float* metapaths = (const float*)d_in[1];
  const float* cardemb = (const float*)d_in[2];
  const float* mpk = (const float*)d_in[3];
  const float* mpbias = (const float*)d_in[4];
  const float* Wq = (const float*)d_in[5];
  const float* bq = (const float*)d_in[6];
  const float* Wk = (const float*)d_in[7];
  const float* bk = (const float*)d_in[8];
  const float* Wv = (const float*)d_in[9];
  const float* bv = (const float*)d_in[10];
  const float* Wo = (const float*)d_in[11];
  const float* bo = (const float*)d_in[12];
  const float* pk = (const float*)d_in[13];
  const float* pb = (const float*)d_in[14];
  float* out = (float*)d_out;
  char* ws = (char*)d_ws;

  ushort* pcA = (ushort*)(ws + PCA_OFF);
  float* part = (float*)(ws + PART_OFF);
  ushort* pcmh = (ushort*)(ws + PCMH_OFF);
  ushort* pcml = (ushort*)(ws + PCML_OFF);
  float* xpart = (float*)(ws + XPART_OFF);
  ushort* npool = (ushort*)(ws + NPOOL_OFF);
  ushort* ncard = (ushort*)(ws + NCARD_OFF);

  k1_pathcard<<<dim3(128, 3), dim3(256), 0, stream>>>(cardemb, mpk, mpbias, pcA);
  k2_big<<<dim3(64, 4, 3), dim3(256), 0, stream>>>(metapaths, pcA, part);
  k2b_reduce<<<dim3(3072), dim3(256), 0, stream>>>(part, pcmh, pcml);
  k3_x<<<dim3(32, 16), dim3(256), 0, stream>>>(pools, pcmh, pcml, xpart);
  k4b_ncard<<<dim3(2048), dim3(256), 0, stream>>>(cardemb, ncard);
  k4_attn<<<dim3(1024), dim3(128), 0, stream>>>(xpart, Wq, bq, Wk, bk, Wv, bv, Wo, bo, pk, pb,
                                                npool);
  k5_out<<<dim3(8, 64), dim3(256), 0, stream>>>(npool, ncard, out);
}